// Round 8
// baseline (112.092 us; speedup 1.0000x reference)
//
#include <hip/hip_runtime.h>

// Problem constants (from reference): B=128, T=256, IN=1, H=5000, OUT=20
#define T_STEPS 256
#define BATCH   128
#define HIDDEN  5000
#define NHALF   2500   // 2 chains per thread: i and i+NHALF
#define NOUT    20
#define NBLK    10     // gridDim.x of the fused kernel
#define CH      16     // x-prefetch chunk (16 floats -> SGPR buffers)

// ---------------------------------------------------------------------------
// Fused kernel: recurrence + head partial-GEMV.
//   h <- tanh(x_t*w + b + h). Track s = c*(h + b), c = 2*log2(e):
//     u  = fma(x, wc, s)              // = c*z
//     E  = exp2(u)                    // hw trans (~16 cyc/wave64) -- the ONLY
//                                     // trans op per chain-step now
//     d  = E + 1
//     y ~= -1/d  via magic seed + 2 sign-alternating Newton steps (main VALU):
//        y0 = bits^-1(0x7EF311C3 - bits(d))   (~ +1/d, |eps| <= 3.4e-2)
//        y1 = y0 * (d*y0 - 2)                 (~ -1/d, eps^2 ~ 1.2e-3)
//        y2 = y1 * (d*y1 + 2)                 (~ -1/d, eps^4 ~ 1.4e-6)
//     tanh = 1 - 2/d = 1 + 2*y2
//     s' = fma(y2, 2c, c + cb)
//   Cost model (fits R1/R3/R6): main ~2 cyc, trans ~16 cyc, serialized.
//   Per chain-step: 8 main + 1 trans (was 3 main + 2 trans = 38 cyc -> 32).
//   NR constants +-1,+-2 are inline constants (free); magic is literal src0.
// Grid: 10 x 128 = 1280 blocks = 5 blocks/CU uniform, 20 waves/CU.
// ---------------------------------------------------------------------------
__global__ __launch_bounds__(256)
void rnn_fused(const float* __restrict__ x,
               const float* __restrict__ W_in,
               const float* __restrict__ b_in,
               const float* __restrict__ W_out,
               float* __restrict__ part) {
    const int b   = blockIdx.y;
    const int tid = threadIdx.x;
    const int i0  = blockIdx.x * 256 + tid;
    const bool valid = (i0 < NHALF);
    const int j0 = valid ? i0 : 0;            // safe index for tail lanes
    const int j1 = j0 + NHALF;

    const float c     = 2.8853900817779268f;   // 2*log2(e)
    const float inv_c = 0.34657359027997264f;  // ln(2)/2
    const float p2c   = 5.7707801635558537f;   // +2c

    const float wc0 = W_in[j0] * c;
    const float wc1 = W_in[j1] * c;
    const float cb0 = b_in[j0] * c;
    const float cb1 = b_in[j1] * c;
    const float cpb0 = c + cb0;                // step constant c + c*b
    const float cpb1 = c + cb1;

    const float* __restrict__ xrow = x + b * T_STEPS;  // wave-uniform reads

    float s0 = cb0, s1 = cb1;                  // s = c*(h+b), h0 = 0

#define STEP1(xv)                                                        \
    {                                                                    \
        const float u0 = fmaf((xv), wc0, s0);                            \
        const float u1 = fmaf((xv), wc1, s1);                            \
        const float E0 = __builtin_amdgcn_exp2f(u0);                     \
        const float E1 = __builtin_amdgcn_exp2f(u1);                     \
        const float d0 = E0 + 1.0f;                                      \
        const float d1 = E1 + 1.0f;                                      \
        float y0 = __uint_as_float(0x7EF311C3u - __float_as_uint(d0));   \
        float y1 = __uint_as_float(0x7EF311C3u - __float_as_uint(d1));   \
        y0 = y0 * fmaf(d0, y0, -2.0f);   /* ~ -1/d0 */                   \
        y1 = y1 * fmaf(d1, y1, -2.0f);                                   \
        y0 = y0 * fmaf(d0, y0,  2.0f);   /* ~ -1/d0, eps^4 */            \
        y1 = y1 * fmaf(d1, y1,  2.0f);                                   \
        s0 = fmaf(y0, p2c, cpb0);        /* c*tanh + c*b */              \
        s1 = fmaf(y1, p2c, cpb1);                                        \
    }

    float a_[CH], b_[CH];
    #pragma unroll
    for (int j = 0; j < CH; ++j) a_[j] = xrow[j];          // chunk 0

    for (int base = 0; base < T_STEPS; base += 2 * CH) {   // 8 iterations
        #pragma unroll
        for (int j = 0; j < CH; ++j) b_[j] = xrow[base + CH + j];
        #pragma unroll
        for (int j = 0; j < CH; ++j) STEP1(a_[j]);
        if (base + 2 * CH < T_STEPS) {
            #pragma unroll
            for (int j = 0; j < CH; ++j) a_[j] = xrow[base + 2 * CH + j];
        }
        #pragma unroll
        for (int j = 0; j < CH; ++j) STEP1(b_[j]);
    }
#undef STEP1

    float h0 = (s0 - cb0) * inv_c;
    float h1 = (s1 - cb1) * inv_c;
    if (!valid) { h0 = 0.0f; h1 = 0.0f; }

    // ---- head partials: acc[o] = h0*W_out[o][j0] + h1*W_out[o][j1] ----
    float acc[NOUT];
    #pragma unroll
    for (int o = 0; o < NOUT; ++o) {
        const float w0 = W_out[o * HIDDEN + j0];    // lane-coalesced
        const float w1 = W_out[o * HIDDEN + j1];
        acc[o] = fmaf(h0, w0, h1 * w1);             // tail lanes contribute 0
    }

    // wave reduce (64 lanes)
    #pragma unroll
    for (int o = 0; o < NOUT; ++o) {
        #pragma unroll
        for (int sft = 32; sft > 0; sft >>= 1)
            acc[o] += __shfl_down(acc[o], sft, 64);
    }

    __shared__ float red[4][NOUT];
    const int wid = tid >> 6, lane = tid & 63;
    if (lane == 0) {
        #pragma unroll
        for (int o = 0; o < NOUT; ++o) red[wid][o] = acc[o];
    }
    __syncthreads();

    if (tid < NOUT) {
        const float v = red[0][tid] + red[1][tid] + red[2][tid] + red[3][tid];
        part[(b * NBLK + blockIdx.x) * NOUT + tid] = v;
    }
}

// ---------------------------------------------------------------------------
// Tiny epilogue: logits[b][o] = sum_blk part + b_out[o]; softmax over 20.
// One wave per batch row; lanes 20..63 padded (-inf for max, 0 for sum).
// ---------------------------------------------------------------------------
__global__ __launch_bounds__(64)
void softmax_head(const float* __restrict__ part,
                  const float* __restrict__ b_out,
                  float* __restrict__ out) {
    const int b = blockIdx.x;
    const int o = threadIdx.x;

    float v = -1e30f;
    if (o < NOUT) {
        float s = b_out[o];
        #pragma unroll
        for (int blk = 0; blk < NBLK; ++blk)
            s += part[(b * NBLK + blk) * NOUT + o];
        v = s;
    }

    float m = v;
    #pragma unroll
    for (int sft = 32; sft > 0; sft >>= 1) m = fmaxf(m, __shfl_xor(m, sft, 64));

    float e = (o < NOUT)
            ? __builtin_amdgcn_exp2f((v - m) * 1.4426950408889634f)
            : 0.0f;
    float ssum = e;
    #pragma unroll
    for (int sft = 32; sft > 0; sft >>= 1) ssum += __shfl_xor(ssum, sft, 64);

    if (o < NOUT) out[b * NOUT + o] = e / ssum;
}

extern "C" void kernel_launch(void* const* d_in, const int* in_sizes, int n_in,
                              void* d_out, int out_size, void* d_ws, size_t ws_size,
                              hipStream_t stream) {
    const float* x     = (const float*)d_in[0];
    const float* W_in  = (const float*)d_in[1];
    const float* b_in  = (const float*)d_in[2];
    const float* W_out = (const float*)d_in[3];
    const float* b_out = (const float*)d_in[4];
    float* out  = (float*)d_out;
    float* part = (float*)d_ws;   // [BATCH][NBLK][NOUT] f32 = 102 KB

    dim3 grid1(NBLK, BATCH);      // 10 x 128
    rnn_fused<<<grid1, 256, 0, stream>>>(x, W_in, b_in, W_out, part);
    softmax_head<<<BATCH, 64, 0, stream>>>(part, b_out, out);
}

// Round 9
// 103.792 us; speedup vs baseline: 1.0800x; 1.0800x over previous
//
#include <hip/hip_runtime.h>

// Problem constants (from reference): B=128, T=256, IN=1, H=5000, OUT=20
#define T_STEPS 256
#define BATCH   128
#define HIDDEN  5000
#define NOUT    20
#define NBLK    20     // gridDim.x of the fused kernel (1 chain/thread)

// ---------------------------------------------------------------------------
// Fused kernel: recurrence + head partial-GEMV. ONE chain per thread.
//   h <- tanh(x_t*w + b + h). Track s = c*(h + b), c = 2*log2(e):
//     u  = fma(x, wc, s)              // = c*z
//     E  = exp2(u)                    // hw trans — the only trans op/step
//     d  = E + 1
//     y ~= -1/d via magic seed + 2 sign-alternating Newton steps (main VALU):
//        y0 = bits^-1(0x7EF311C3 - bits(d))   (~ +1/d)
//        y1 = y0 * (d*y0 - 2)                 (~ -1/d, eps^2)
//        y2 = y1 * (d*y1 + 2)                 (~ -1/d, eps^4 ~ 1e-6)
//     tanh = 1 + 2*y2;  s' = fma(y2, 2c, c + cb)
//   Per step: 8 main + 1 trans.
//
// A/B vs R7 (which used the SAME arithmetic but 2 chains/thread, 5 waves/SIMD
// and regressed to 56 us): this uses 1 chain/thread in the R1 layout
// (2560 blocks, 8 waves/SIMD resident, 1.25 dispatch rounds) — short dep
// chain, small unrolled body, maximum wave-level latency hiding.
// Issue model (fits R1/R3/R6 within 5%): main=2cyc, trans=16cyc per wave64.
// Round-1 prediction: 8 waves x 32 cyc = 256 cyc/SIMD-step.
// ---------------------------------------------------------------------------
__global__ __launch_bounds__(256)
void rnn_fused(const float* __restrict__ x,
               const float* __restrict__ W_in,
               const float* __restrict__ b_in,
               const float* __restrict__ W_out,
               float* __restrict__ part) {
    const int b   = blockIdx.y;
    const int tid = threadIdx.x;
    const int i0  = blockIdx.x * 256 + tid;
    const bool valid = (i0 < HIDDEN);
    const int j0 = valid ? i0 : 0;             // safe index for tail lanes

    const float c     = 2.8853900817779268f;   // 2*log2(e)
    const float inv_c = 0.34657359027997264f;  // ln(2)/2
    const float p2c   = 5.7707801635558537f;   // +2c

    const float wc  = W_in[j0] * c;
    const float cb  = b_in[j0] * c;
    const float cpb = c + cb;                  // step constant c + c*b

    const float* __restrict__ xrow = x + b * T_STEPS;  // wave-uniform reads

    float s = cb;                              // s = c*(h+b), h0 = 0

    #pragma unroll 8
    for (int t = 0; t < T_STEPS; ++t) {
        const float xv = xrow[t];              // uniform -> s_load
        const float u  = fmaf(xv, wc, s);
        const float E  = __builtin_amdgcn_exp2f(u);
        const float d  = E + 1.0f;
        float y = __uint_as_float(0x7EF311C3u - __float_as_uint(d));
        y = y * fmaf(d, y, -2.0f);             // ~ -1/d
        y = y * fmaf(d, y,  2.0f);             // ~ -1/d, eps^4
        s = fmaf(y, p2c, cpb);                 // c*tanh + c*b
    }

    float h = valid ? (s - cb) * inv_c : 0.0f;

    // ---- head partials: acc[o] = h * W_out[o][j0] ----
    float acc[NOUT];
    #pragma unroll
    for (int o = 0; o < NOUT; ++o) {
        acc[o] = h * W_out[o * HIDDEN + j0];   // lane-coalesced, L2-hot
    }

    // wave reduce (64 lanes)
    #pragma unroll
    for (int o = 0; o < NOUT; ++o) {
        #pragma unroll
        for (int sft = 32; sft > 0; sft >>= 1)
            acc[o] += __shfl_down(acc[o], sft, 64);
    }

    __shared__ float red[4][NOUT];
    const int wid = tid >> 6, lane = tid & 63;
    if (lane == 0) {
        #pragma unroll
        for (int o = 0; o < NOUT; ++o) red[wid][o] = acc[o];
    }
    __syncthreads();

    if (tid < NOUT) {
        const float v = red[0][tid] + red[1][tid] + red[2][tid] + red[3][tid];
        part[(b * NBLK + blockIdx.x) * NOUT + tid] = v;
    }
}

// ---------------------------------------------------------------------------
// Tiny epilogue: logits[b][o] = sum_blk part + b_out[o]; softmax over 20.
// One wave per batch row; lanes 20..63 padded (-inf for max, 0 for sum).
// ---------------------------------------------------------------------------
__global__ __launch_bounds__(64)
void softmax_head(const float* __restrict__ part,
                  const float* __restrict__ b_out,
                  float* __restrict__ out) {
    const int b = blockIdx.x;
    const int o = threadIdx.x;

    float v = -1e30f;
    if (o < NOUT) {
        float s = b_out[o];
        #pragma unroll
        for (int blk = 0; blk < NBLK; ++blk)
            s += part[(b * NBLK + blk) * NOUT + o];
        v = s;
    }

    float m = v;
    #pragma unroll
    for (int sft = 32; sft > 0; sft >>= 1) m = fmaxf(m, __shfl_xor(m, sft, 64));

    float e = (o < NOUT)
            ? __builtin_amdgcn_exp2f((v - m) * 1.4426950408889634f)
            : 0.0f;
    float ssum = e;
    #pragma unroll
    for (int sft = 32; sft > 0; sft >>= 1) ssum += __shfl_xor(ssum, sft, 64);

    if (o < NOUT) out[b * NOUT + o] = e / ssum;
}

extern "C" void kernel_launch(void* const* d_in, const int* in_sizes, int n_in,
                              void* d_out, int out_size, void* d_ws, size_t ws_size,
                              hipStream_t stream) {
    const float* x     = (const float*)d_in[0];
    const float* W_in  = (const float*)d_in[1];
    const float* b_in  = (const float*)d_in[2];
    const float* W_out = (const float*)d_in[3];
    const float* b_out = (const float*)d_in[4];
    float* out  = (float*)d_out;
    float* part = (float*)d_ws;   // [BATCH][NBLK][NOUT] f32 = 204.8 KB

    dim3 grid1(NBLK, BATCH);      // 20 x 128 = 2560 blocks, 1 chain/thread
    rnn_fused<<<grid1, 256, 0, stream>>>(x, W_in, b_in, W_out, part);
    softmax_head<<<BATCH, 64, 0, stream>>>(part, b_out, out);
}